// Round 10
// baseline (339.632 us; speedup 1.0000x reference)
//
#include <hip/hip_runtime.h>
#include <math.h>

#define N_TOK 16384
#define DM    2048
#define NE    64
#define TOPK  4

#define OFF_TI  0
#define OFF_TS  (N_TOK * TOPK)
#define OFF_SC  (2 * N_TOK * TOPK)
#define OFF_AUX (2 * N_TOK * TOPK + N_TOK * NE)

// ---------------- MFMA path (R7 geometry) ----------------
#define MTPB  64             // tokens per block -> grid 256 = 1 block/CU
#define RW    128            // dims per staged round
#define NRND  (DM / RW)      // 16
#define KSTR  136            // u bf16 plane row stride (128 + 8 pad)
#define PLN   (MTPB * KSTR)  // 8704 bf16 per plane (17408 B)

#define EH_OFF   1024                      // byte offset of packed Eh in ws
#define ET_ELEMS ((size_t)NE * DM)         // 131072 bf16 per table
#define WS_NEED  (EH_OFF + 4 * ET_ELEMS)   // 525,312 B

typedef short s8v __attribute__((ext_vector_type(8)));   // 8 bf16 = 4 VGPR
typedef float f4v __attribute__((ext_vector_type(4)));

__device__ __forceinline__ unsigned short bf16_rne(float x) {
  unsigned int b = __float_as_uint(x);
  b += 0x7FFFu + ((b >> 16) & 1u);
  return (unsigned short)(b >> 16);
}

// E[2048][64] f32 -> PACKED B-fragment layout (R6/R7-verified), hi/lo bf16.
// Also zeroes ws[0..127].
__global__ __launch_bounds__(256) void router_prep(
    const float* __restrict__ E, unsigned short* __restrict__ eh,
    unsigned short* __restrict__ el, float* __restrict__ ws)
{
  __shared__ float t[32][65];
  const int tid = threadIdx.x;
  if (blockIdx.x == 0 && tid < 128) ws[tid] = 0.f;
  const int k0  = blockIdx.x * 32;          // = pk * 32
#pragma unroll
  for (int i = 0; i < 2; ++i) {
    const int fi = i * 256 + tid;
    const int kk = fi >> 4, ee = (fi & 15) * 4;
    const float4 v = *(const float4*)(E + (size_t)(k0 + kk) * NE + ee);
    t[kk][ee] = v.x; t[kk][ee + 1] = v.y; t[kk][ee + 2] = v.z; t[kk][ee + 3] = v.w;
  }
  __syncthreads();
  const int j    = tid >> 6;
  const int lane = tid & 63;
  const int ex   = j * 16 + (lane & 15);
  const int kb   = (lane >> 4) * 8;
  unsigned int hw[4], lw[4];
#pragma unroll
  for (int p = 0; p < 4; ++p) {
    unsigned short h[2], l[2];
#pragma unroll
    for (int q = 0; q < 2; ++q) {
      const float x = t[kb + p * 2 + q][ex];
      h[q] = bf16_rne(x);
      l[q] = bf16_rne(x - __uint_as_float((unsigned)h[q] << 16));
    }
    hw[p] = (unsigned)h[0] | ((unsigned)h[1] << 16);
    lw[p] = (unsigned)l[0] | ((unsigned)l[1] << 16);
  }
  const size_t o = (size_t)blockIdx.x * 2048 + j * 512 + lane * 8;
  *(uint4*)(eh + o) = make_uint4(hw[0], hw[1], hw[2], hw[3]);
  *(uint4*)(el + o) = make_uint4(lw[0], lw[1], lw[2], lw[3]);
}

// ---- shared macros (R7-verbatim staging) ----
#define LOAD_U(pf, r) do { _Pragma("unroll") \
  for (int i_ = 0; i_ < 8; ++i_) \
    pf[i_] = *(const float4*)(ugp + (size_t)(r) * RW + i_ * 16); } while (0)

#define WRITE_U(pf, base) do { _Pragma("unroll") \
  for (int i_ = 0; i_ < 8; ++i_) { \
    const float4 v_ = pf[i_]; \
    const unsigned short h0_ = bf16_rne(v_.x), h1_ = bf16_rne(v_.y), \
                         h2_ = bf16_rne(v_.z), h3_ = bf16_rne(v_.w); \
    const unsigned short l0_ = bf16_rne(v_.x - __uint_as_float((unsigned)h0_ << 16)); \
    const unsigned short l1_ = bf16_rne(v_.y - __uint_as_float((unsigned)h1_ << 16)); \
    const unsigned short l2_ = bf16_rne(v_.z - __uint_as_float((unsigned)h2_ << 16)); \
    const unsigned short l3_ = bf16_rne(v_.w - __uint_as_float((unsigned)h3_ << 16)); \
    *(uint2*)&sh[(base) + uoff + i_ * 16] = \
      make_uint2((unsigned)h0_ | ((unsigned)h1_ << 16), (unsigned)h2_ | ((unsigned)h3_ << 16)); \
    *(uint2*)&sh[(base) + PLN + uoff + i_ * 16] = \
      make_uint2((unsigned)l0_ | ((unsigned)l1_ << 16), (unsigned)l2_ | ((unsigned)l3_ << 16)); \
  } } while (0)

#define COMPUTE(r, base) do { \
    const int    pk_ = (r) * 4 + kq; \
    const size_t pb_ = (size_t)pk_ * 2048 + lane * 8; \
    s8v ah_[4], al_[4]; \
    _Pragma("unroll") for (int tt_ = 0; tt_ < 4; ++tt_) { \
      ah_[tt_] = *(const s8v*)&sh[(base) + a_off + tt_ * (16 * KSTR)]; \
      al_[tt_] = *(const s8v*)&sh[(base) + PLN + a_off + tt_ * (16 * KSTR)]; \
    } \
    _Pragma("unroll") for (int j_ = 0; j_ < 4; ++j_) { \
      const s8v bh_ = *(const s8v*)&eh[pb_ + j_ * 512]; \
      const s8v bl_ = *(const s8v*)&el[pb_ + j_ * 512]; \
      _Pragma("unroll") for (int tt_ = 0; tt_ < 4; ++tt_) { \
        acc[tt_][j_] = __builtin_amdgcn_mfma_f32_16x16x32_bf16(ah_[tt_], bh_, acc[tt_][j_], 0, 0, 0); \
        acc[tt_][j_] = __builtin_amdgcn_mfma_f32_16x16x32_bf16(ah_[tt_], bl_, acc[tt_][j_], 0, 0, 0); \
        acc[tt_][j_] = __builtin_amdgcn_mfma_f32_16x16x32_bf16(al_[tt_], bh_, acc[tt_][j_], 0, 0, 0); \
        acc[tt_][j_] = __builtin_amdgcn_mfma_f32_16x16x32_bf16(al_[tt_], bl_, acc[tt_][j_], 0, 0, 0); \
      } } } while (0)

// same as COMPUTE but MFMAs replaced by keep-alives (rule #17: ablation-via-skip
// DCEs upstream ops; asm "v" keeps each b128/ds_read live at zero cost)
#define COMPUTE_MEM(r, base) do { \
    const int    pk_ = (r) * 4 + kq; \
    const size_t pb_ = (size_t)pk_ * 2048 + lane * 8; \
    _Pragma("unroll") for (int tt_ = 0; tt_ < 4; ++tt_) { \
      s8v ah_ = *(const s8v*)&sh[(base) + a_off + tt_ * (16 * KSTR)]; \
      s8v al_ = *(const s8v*)&sh[(base) + PLN + a_off + tt_ * (16 * KSTR)]; \
      asm volatile("" :: "v"(*(const int*)&ah_), "v"(*(const int*)&al_)); \
    } \
    _Pragma("unroll") for (int j_ = 0; j_ < 4; ++j_) { \
      s8v bh_ = *(const s8v*)&eh[pb_ + j_ * 512]; \
      s8v bl_ = *(const s8v*)&el[pb_ + j_ * 512]; \
      asm volatile("" :: "v"(*(const int*)&bh_), "v"(*(const int*)&bl_)); \
    } } while (0)

// ======== PROBE 1: per-dispatch tax ========
__global__ __launch_bounds__(256, 1) void probe_empty() {
  asm volatile("");
}

// ======== PROBE 2: R7 minus MFMA (u staging + cvt + LDS + E loads + barriers) ========
__global__ __launch_bounds__(256, 1) void probe_nomfma(
    const float* __restrict__ u, const unsigned short* __restrict__ eh,
    const unsigned short* __restrict__ el)
{
  __shared__ __align__(16) unsigned short sh[4 * PLN];
  const int tid  = threadIdx.x;
  const int lane = tid & 63;
  const int kq   = __builtin_amdgcn_readfirstlane(tid >> 6);
  const int lm   = lane & 15;
  const int lk   = lane >> 4;
  const int tok0 = blockIdx.x * MTPB;
  const int srow = tid >> 2, sseg = tid & 3;
  const float* ugp = u + (size_t)(tok0 + srow) * DM + sseg * 4;
  const int uoff = srow * KSTR + sseg * 4;
  const int a_off = lm * KSTR + kq * 32 + lk * 8;

  float4 pfA[8], pfB[8];
  LOAD_U(pfA, 0);
  LOAD_U(pfB, 1);
  WRITE_U(pfA, 0);
  __syncthreads();
  for (int rr = 0; rr < NRND; rr += 2) {
    WRITE_U(pfB, 2 * PLN);
    if (rr + 2 < NRND) LOAD_U(pfA, rr + 2);
    COMPUTE_MEM(rr, 0);
    __syncthreads();
    if (rr + 2 < NRND) WRITE_U(pfA, 0);
    if (rr + 3 < NRND) LOAD_U(pfB, rr + 3);
    COMPUTE_MEM(rr + 1, 2 * PLN);
    __syncthreads();
  }
}

// ======== PROBE 3: R7 minus u path (const A; E loads + MFMA + barriers) ========
__global__ __launch_bounds__(256, 1) void probe_nou(
    const unsigned short* __restrict__ eh, const unsigned short* __restrict__ el)
{
  const int tid  = threadIdx.x;
  const int lane = tid & 63;
  const int kq   = __builtin_amdgcn_readfirstlane(tid >> 6);

  s8v ac;
#pragma unroll
  for (int i = 0; i < 8; ++i) ac[i] = (short)0x3f80;

  f4v acc[4][4];
#pragma unroll
  for (int t = 0; t < 4; ++t)
#pragma unroll
    for (int j = 0; j < 4; ++j) acc[t][j] = (f4v){0.f, 0.f, 0.f, 0.f};

  for (int r = 0; r < NRND; ++r) {
    const int    pk = r * 4 + kq;
    const size_t pb = (size_t)pk * 2048 + lane * 8;
#pragma unroll
    for (int j = 0; j < 4; ++j) {
      const s8v bh = *(const s8v*)&eh[pb + j * 512];
      const s8v bl = *(const s8v*)&el[pb + j * 512];
#pragma unroll
      for (int t = 0; t < 4; ++t) {
        acc[t][j] = __builtin_amdgcn_mfma_f32_16x16x32_bf16(ac, bh, acc[t][j], 0, 0, 0);
        acc[t][j] = __builtin_amdgcn_mfma_f32_16x16x32_bf16(ac, bl, acc[t][j], 0, 0, 0);
        acc[t][j] = __builtin_amdgcn_mfma_f32_16x16x32_bf16(ac, bh, acc[t][j], 0, 0, 0);
        acc[t][j] = __builtin_amdgcn_mfma_f32_16x16x32_bf16(ac, bl, acc[t][j], 0, 0, 0);
      }
    }
    __syncthreads();
  }
#pragma unroll
  for (int t = 0; t < 4; ++t)
#pragma unroll
    for (int j = 0; j < 4; ++j)
      asm volatile("" :: "v"(acc[t][j][0]), "v"(acc[t][j][3]));
}

// ======== MAIN: R7-verbatim (best passing, 136us) ========
__global__ __launch_bounds__(256, 1) void router_main_mfma(
    const float* __restrict__ u, const unsigned short* __restrict__ eh,
    const unsigned short* __restrict__ el, const float* __restrict__ bias,
    float* __restrict__ out, float* __restrict__ ws)
{
  __shared__ __align__(16) unsigned short sh[4 * PLN];   // 69,632 B

  const int tid  = threadIdx.x;
  const int lane = tid & 63;
  const int kq   = __builtin_amdgcn_readfirstlane(tid >> 6);
  const int lm   = lane & 15;
  const int lk   = lane >> 4;
  const int tok0 = blockIdx.x * MTPB;

  const int srow = tid >> 2, sseg = tid & 3;
  const float* ugp = u + (size_t)(tok0 + srow) * DM + sseg * 4;
  const int uoff = srow * KSTR + sseg * 4;
  const int a_off = lm * KSTR + kq * 32 + lk * 8;

  f4v acc[4][4];
#pragma unroll
  for (int t = 0; t < 4; ++t)
#pragma unroll
    for (int j = 0; j < 4; ++j) acc[t][j] = (f4v){0.f, 0.f, 0.f, 0.f};

  float4 pfA[8], pfB[8];
  LOAD_U(pfA, 0);
  LOAD_U(pfB, 1);
  WRITE_U(pfA, 0);
  __syncthreads();

  for (int rr = 0; rr < NRND; rr += 2) {
    WRITE_U(pfB, 2 * PLN);
    if (rr + 2 < NRND) LOAD_U(pfA, rr + 2);
    COMPUTE(rr, 0);
    __syncthreads();
    if (rr + 2 < NRND) WRITE_U(pfA, 0);
    if (rr + 3 < NRND) LOAD_U(pfB, rr + 3);
    COMPUTE(rr + 1, 2 * PLN);
    __syncthreads();
  }

  float* fin = (float*)sh;
  if (kq < 2) {
#pragma unroll
    for (int t = 0; t < 4; ++t)
#pragma unroll
      for (int j = 0; j < 4; ++j)
#pragma unroll
        for (int q = 0; q < 4; ++q)
          fin[kq * (64 * 68) + (t * 16 + lk * 4 + q) * 68 + j * 16 + lm] = acc[t][j][q];
  }
  __syncthreads();
  if (kq >= 2) {
#pragma unroll
    for (int t = 0; t < 4; ++t)
#pragma unroll
      for (int j = 0; j < 4; ++j)
#pragma unroll
        for (int q = 0; q < 4; ++q)
          fin[(kq - 2) * (64 * 68) + (t * 16 + lk * 4 + q) * 68 + j * 16 + lm] += acc[t][j][q];
  }
  __syncthreads();

  const float be = bias[lane];
  float asum = 0.f;
  for (int tt = 0; tt < 16; ++tt) {
    const int t = kq * 16 + tt;
    float x = fin[t * 68 + lane] + fin[64 * 68 + t * 68 + lane] + be;

    float m = x;
#pragma unroll
    for (int off = 32; off > 0; off >>= 1) m = fmaxf(m, __shfl_xor(m, off));
    float p = expf(x - m);
    float s = p;
#pragma unroll
    for (int off = 32; off > 0; off >>= 1) s += __shfl_xor(s, off);
    float sc = p / s;

    out[OFF_SC + (size_t)(tok0 + t) * NE + lane] = sc;
    asum += sc;

    float v = sc;
#pragma unroll
    for (int k = 0; k < TOPK; ++k) {
      float bv = v;
      int   bi = lane;
#pragma unroll
      for (int off = 32; off > 0; off >>= 1) {
        float ov = __shfl_xor(bv, off);
        int   oi = __shfl_xor(bi, off);
        if (ov > bv || (ov == bv && oi < bi)) { bv = ov; bi = oi; }
      }
      if (lane == k) {
        out[OFF_TI + (size_t)(tok0 + t) * TOPK + k] = (float)bi;
        out[OFF_TS + (size_t)(tok0 + t) * TOPK + k] = bv;
      }
      if (lane == bi) v = -INFINITY;
    }
  }
  atomicAdd(&ws[lane], asum);

  __threadfence();
  __syncthreads();
  unsigned* flg = (unsigned*)sh;
  if (tid == 0) {
    const unsigned t = atomicAdd((unsigned*)&ws[NE], 1u);
    flg[9216] = (t == (unsigned)(gridDim.x - 1)) ? 1u : 0u;
  }
  __syncthreads();
  if (flg[9216] && tid < 64) {
    const float mv = atomicAdd(&ws[tid], 0.f) * (1.0f / N_TOK);
    float v = mv * mv;
#pragma unroll
    for (int off = 32; off > 0; off >>= 1) v += __shfl_xor(v, off);
    if (tid == 0) out[OFF_AUX] = v * (float)NE;
  }
}

// ---------------- fallback (ws too small): proven R1 kernel ----------------
#define TPB     64
#define FB_DC   32
#define FB_NCH  (1024 / FB_DC)
#define FB_LSTR 68
#define FB_UB   (TPB * FB_LSTR)
#define FB_EOFF (2 * FB_UB)
#define FB_EB   (2 * FB_DC * NE)

__global__ __launch_bounds__(1024, 4) void router_main_fb(
    const float* __restrict__ u, const float* __restrict__ E,
    const float* __restrict__ bias, float* __restrict__ out,
    float* __restrict__ ws)
{
  __shared__ float smem[FB_EOFF + 2 * FB_EB];

  const int tid  = threadIdx.x;
  const int lane = tid & 63;
  const int wid  = __builtin_amdgcn_readfirstlane(tid >> 6);
  const int eg   = wid & 7;
  const int kh   = wid >> 3;
  const int tok0 = blockIdx.x * TPB;

  const int stok  = tid >> 4;
  const int sdseg = tid & 15;
  const int skh   = sdseg >> 3;
  const int sdsub = (sdseg & 7) * 4;
  const float* sgbase = u + (size_t)(tok0 + stok) * DM + skh * 1024 + sdsub;
  float* swp = smem + stok * FB_LSTR + sdseg * 4;

  const int eq  = tid & 511;
  const int ekh = tid >> 9;
  const float* egbase = E + (size_t)ekh * 1024 * NE + eq * 4;
  float* ewp = smem + FB_EOFF + ekh * (FB_DC * NE) + eq * 4;

  float acc[8];
#pragma unroll
  for (int j = 0; j < 8; ++j) acc[j] = 0.f;

  float4 pf[3];
  pf[0] = *(const float4*)(sgbase + 0 * FB_DC);
  pf[1] = *(const float4*)(sgbase + 1 * FB_DC);
  pf[2] = *(const float4*)(sgbase + 2 * FB_DC);
  float4 epf = *(const float4*)(egbase + 0 * (FB_DC * NE));
  *(float4*)(swp + 0) = pf[0];
  *(float4*)(ewp + 0) = epf;
  epf = *(const float4*)(egbase + 1 * (FB_DC * NE));
  __syncthreads();

  for (int c = 0; c < FB_NCH; ++c) {
    if (c + 1 < FB_NCH) {
      *(float4*)(swp + ((c + 1) & 1) * FB_UB) = pf[(c + 1) % 3];
      *(float4*)(ewp + ((c + 1) & 1) * FB_EB) = epf;
    }
    if (c + 2 < FB_NCH)
      epf = *(const float4*)(egbase + (c + 2) * (FB_DC * NE));
    if (c + 3 < FB_NCH)
      pf[c % 3] = *(const float4*)(sgbase + (c + 3) * FB_DC);

    const float* sb = smem + (c & 1) * FB_UB + lane * FB_LSTR + kh * FB_DC;
    const float* eb = smem + FB_EOFF + (c & 1) * FB_EB + kh * (FB_DC * NE) + eg * 8;
#pragma unroll
    for (int s = 0; s < 8; ++s) {
      float4 uf = *(const float4*)(sb + s * 4);
#pragma unroll
      for (int dd = 0; dd < 4; ++dd) {
        const float* er = eb + (s * 4 + dd) * NE;
        float4 e0 = *(const float4*)(er);
        float4 e1 = *(const float4*)(er + 4);
        const float uv = (&uf.x)[dd];
        acc[0] = fmaf(e0.x, uv, acc[0]);
        acc[1] = fmaf(e0.y, uv, acc[1]);
        acc[2] = fmaf(e0.z, uv, acc[2]);
        acc[3] = fmaf(e0.w, uv, acc[3]);
        acc[4] = fmaf(e1.x, uv, acc[4]);
        acc[5] = fmaf(e1.y, uv, acc[5]);
        acc[6] = fmaf(e1.z, uv, acc[6]);
        acc[7] = fmaf(e1.w, uv, acc[7]);
      }
    }
    __syncthreads();
  }

  float* fin = smem;
  if (kh == 0) {
#pragma unroll
    for (int j = 0; j < 8; ++j) fin[lane * 65 + eg * 8 + j] = acc[j];
  }
  __syncthreads();
  if (kh == 1) {
#pragma unroll
    for (int j = 0; j < 8; ++j) fin[lane * 65 + eg * 8 + j] += acc[j];
  }
  __syncthreads();

  const float be = bias[lane];
  float asum = 0.f;
#pragma unroll
  for (int tt = 0; tt < 4; ++tt) {
    const int t = wid * 4 + tt;
    float x = fin[t * 65 + lane] + be;

    float m = x;
#pragma unroll
    for (int off = 32; off > 0; off >>= 1) m = fmaxf(m, __shfl_xor(m, off));
    float p = expf(x - m);
    float s = p;
#pragma unroll
    for (int off = 32; off > 0; off >>= 1) s += __shfl_xor(s, off);
    float sc = p / s;

    out[OFF_SC + (size_t)(tok0 + t) * NE + lane] = sc;
    asum += sc;

    float v = sc;
#pragma unroll
    for (int k = 0; k < TOPK; ++k) {
      float bv = v;
      int   bi = lane;
#pragma unroll
      for (int off = 32; off > 0; off >>= 1) {
        float ov = __shfl_xor(bv, off);
        int   oi = __shfl_xor(bi, off);
        if (ov > bv || (ov == bv && oi < bi)) { bv = ov; bi = oi; }
      }
      if (lane == k) {
        out[OFF_TI + (size_t)(tok0 + t) * TOPK + k] = (float)bi;
        out[OFF_TS + (size_t)(tok0 + t) * TOPK + k] = bv;
      }
      if (lane == bi) v = -INFINITY;
    }
  }
  atomicAdd(&ws[lane], asum);
}

__global__ void router_aux(const float* __restrict__ ws, float* __restrict__ out)
{
  const int lane = threadIdx.x & 63;
  float m = ws[lane] * (1.0f / N_TOK);
  float v = m * m;
#pragma unroll
  for (int off = 32; off > 0; off >>= 1) v += __shfl_xor(v, off);
  if (lane == 0) out[OFF_AUX] = v * (float)NE;
}

extern "C" void kernel_launch(void* const* d_in, const int* in_sizes, int n_in,
                              void* d_out, int out_size, void* d_ws, size_t ws_size,
                              hipStream_t stream) {
  const float* u    = (const float*)d_in[0];
  const float* E    = (const float*)d_in[1];
  const float* bias = (const float*)d_in[2];
  float* out = (float*)d_out;
  float* ws  = (float*)d_ws;

  if (ws_size >= WS_NEED) {
    unsigned short* eh = (unsigned short*)((char*)ws + EH_OFF);
    unsigned short* el = eh + ET_ELEMS;
    router_prep<<<DM / 32, 256, 0, stream>>>(E, eh, el, ws);
    // ---- instrumentation probes (store-free, cannot affect outputs) ----
    probe_empty<<<N_TOK / MTPB, 256, 0, stream>>>();
    probe_nomfma<<<N_TOK / MTPB, 256, 0, stream>>>(u, eh, el);
    probe_nou<<<N_TOK / MTPB, 256, 0, stream>>>(eh, el);
    // ---- real kernel (R7-verbatim) ----
    router_main_mfma<<<N_TOK / MTPB, 256, 0, stream>>>(u, eh, el, bias, out, ws);
  } else {
    hipMemsetAsync(ws, 0, NE * sizeof(float), stream);
    router_main_fb<<<N_TOK / TPB, 1024, 0, stream>>>(u, E, bias, out, ws);
    router_aux<<<1, 64, 0, stream>>>(ws, out);
  }
}

// Round 11
// 322.153 us; speedup vs baseline: 1.0543x; 1.0543x over previous
//
#include <hip/hip_runtime.h>
#include <math.h>

#define N_TOK 16384
#define DM    2048
#define NE    64
#define TOPK  4

#define OFF_TI  0
#define OFF_TS  (N_TOK * TOPK)
#define OFF_SC  (2 * N_TOK * TOPK)
#define OFF_AUX (2 * N_TOK * TOPK + N_TOK * NE)

// ---------------- MFMA path: barrier-free K-loop ----------------
// 512 thr = 8 waves = 4 token-groups (g) x 2 K-halves (h); 64 tok/block,
// grid 256 = 1 block/CU, 2 waves/SIMD.
#define MTPB  64
#define RW2   128            // dims per round per wave
#define NR2   8              // rounds per K-half
#define KS2   136            // u bf16 row stride (128 + 8 pad)
#define WPLH  (16 * KS2)     // one 16-token plane (hi or lo) = 2176 bf16
#define WPL   (2 * WPLH)     // per-wave private region = 8704 B

#define EH_OFF   1024                      // byte offset of packed Eh in ws
#define ET_ELEMS ((size_t)NE * DM)         // 131072 bf16 per table
#define WS_NEED  (EH_OFF + 4 * ET_ELEMS)   // 525,312 B

typedef short s8v __attribute__((ext_vector_type(8)));   // 8 bf16 = 4 VGPR
typedef float f4v __attribute__((ext_vector_type(4)));

__device__ __forceinline__ unsigned short bf16_rne(float x) {
  unsigned int b = __float_as_uint(x);
  b += 0x7FFFu + ((b >> 16) & 1u);
  return (unsigned short)(b >> 16);
}

// E[2048][64] f32 -> PACKED B-fragment layout (R6/R7-verified), hi/lo bf16:
//   EP[pk][j][lane][q]: expert = j*16+(lane&15), k = pk*32+(lane>>4)*8+q.
// Also zeroes ws[0..127] (per-expert partials + ticket counter).
__global__ __launch_bounds__(256) void router_prep(
    const float* __restrict__ E, unsigned short* __restrict__ eh,
    unsigned short* __restrict__ el, float* __restrict__ ws)
{
  __shared__ float t[32][65];
  const int tid = threadIdx.x;
  if (blockIdx.x == 0 && tid < 128) ws[tid] = 0.f;
  const int k0  = blockIdx.x * 32;          // = pk * 32
#pragma unroll
  for (int i = 0; i < 2; ++i) {
    const int fi = i * 256 + tid;
    const int kk = fi >> 4, ee = (fi & 15) * 4;
    const float4 v = *(const float4*)(E + (size_t)(k0 + kk) * NE + ee);
    t[kk][ee] = v.x; t[kk][ee + 1] = v.y; t[kk][ee + 2] = v.z; t[kk][ee + 3] = v.w;
  }
  __syncthreads();
  const int j    = tid >> 6;
  const int lane = tid & 63;
  const int ex   = j * 16 + (lane & 15);
  const int kb   = (lane >> 4) * 8;
  unsigned int hw[4], lw[4];
#pragma unroll
  for (int p = 0; p < 4; ++p) {
    unsigned short h[2], l[2];
#pragma unroll
    for (int q = 0; q < 2; ++q) {
      const float x = t[kb + p * 2 + q][ex];
      h[q] = bf16_rne(x);
      l[q] = bf16_rne(x - __uint_as_float((unsigned)h[q] << 16));
    }
    hw[p] = (unsigned)h[0] | ((unsigned)h[1] << 16);
    lw[p] = (unsigned)l[0] | ((unsigned)l[1] << 16);
  }
  const size_t o = (size_t)blockIdx.x * 2048 + j * 512 + lane * 8;
  *(uint4*)(eh + o) = make_uint4(hw[0], hw[1], hw[2], hw[3]);
  *(uint4*)(el + o) = make_uint4(lw[0], lw[1], lw[2], lw[3]);
}

// R10 partition result: u-skeleton probe and E+MFMA probe EACH run ~10-25us;
// full kernel 137us. The wall is the INTERACTION: per-round __syncthreads
// forces vmcnt(0)+lgkmcnt(0) drains, and in-order vmcnt queues E-loads behind
// u-prefetch loads -> every round serially eats the full u round-trip.
// Fix here: ZERO barriers in the K-loop. Wave (g,h) owns tokens g*16..+15,
// dims h*1024..+1023; stages u into its PRIVATE LDS region (same-wave
// global->reg->cvt->ds_write, in-order DS, counted lgkm by compiler); reads
// its own A-frags; E streams via normal dataflow (counted vmcnt). Cross-wave
// K-half reduction: 3 barriers total at the end. Numerics R7-verbatim.
#define LOADW(pf, r) do { _Pragma("unroll") \
  for (int i_ = 0; i_ < 8; ++i_) \
    pf[i_] = *(const float4*)(ugw + (size_t)(r) * RW2 + i_ * 16); } while (0)

#define WRITEW(pf) do { _Pragma("unroll") \
  for (int i_ = 0; i_ < 8; ++i_) { \
    const float4 v_ = pf[i_]; \
    const unsigned short h0_ = bf16_rne(v_.x), h1_ = bf16_rne(v_.y), \
                         h2_ = bf16_rne(v_.z), h3_ = bf16_rne(v_.w); \
    const unsigned short l0_ = bf16_rne(v_.x - __uint_as_float((unsigned)h0_ << 16)); \
    const unsigned short l1_ = bf16_rne(v_.y - __uint_as_float((unsigned)h1_ << 16)); \
    const unsigned short l2_ = bf16_rne(v_.z - __uint_as_float((unsigned)h2_ << 16)); \
    const unsigned short l3_ = bf16_rne(v_.w - __uint_as_float((unsigned)h3_ << 16)); \
    *(uint2*)&shw[uoffw + i_ * 16] = \
      make_uint2((unsigned)h0_ | ((unsigned)h1_ << 16), (unsigned)h2_ | ((unsigned)h3_ << 16)); \
    *(uint2*)&shw[WPLH + uoffw + i_ * 16] = \
      make_uint2((unsigned)l0_ | ((unsigned)l1_ << 16), (unsigned)l2_ | ((unsigned)l3_ << 16)); \
  } } while (0)

#define READF(Fh, Fl) do { _Pragma("unroll") \
  for (int p_ = 0; p_ < 4; ++p_) { \
    Fh[p_] = *(const s8v*)&shw[a_off + p_ * 32]; \
    Fl[p_] = *(const s8v*)&shw[WPLH + a_off + p_ * 32]; \
  } } while (0)

#define COMP(r, Fh, Fl) do { \
    const size_t pbase_ = ((size_t)(h * 32 + (r) * 4)) * 2048 + lane * 8; \
    _Pragma("unroll") for (int p_ = 0; p_ < 4; ++p_) { \
      const size_t pb_ = pbase_ + (size_t)p_ * 2048; \
      _Pragma("unroll") for (int j_ = 0; j_ < 4; ++j_) { \
        const s8v bh_ = *(const s8v*)&eh[pb_ + j_ * 512]; \
        const s8v bl_ = *(const s8v*)&el[pb_ + j_ * 512]; \
        acc[j_] = __builtin_amdgcn_mfma_f32_16x16x32_bf16(Fh[p_], bh_, acc[j_], 0, 0, 0); \
        acc[j_] = __builtin_amdgcn_mfma_f32_16x16x32_bf16(Fh[p_], bl_, acc[j_], 0, 0, 0); \
        acc[j_] = __builtin_amdgcn_mfma_f32_16x16x32_bf16(Fl[p_], bh_, acc[j_], 0, 0, 0); \
        acc[j_] = __builtin_amdgcn_mfma_f32_16x16x32_bf16(Fl[p_], bl_, acc[j_], 0, 0, 0); \
      } } } while (0)

__global__ __launch_bounds__(512, 1) void router_main_mfma(
    const float* __restrict__ u, const unsigned short* __restrict__ eh,
    const unsigned short* __restrict__ el, const float* __restrict__ bias,
    float* __restrict__ out, float* __restrict__ ws)
{
  __shared__ __align__(16) unsigned short sh[8 * WPL];   // 69,632 B

  const int tid  = threadIdx.x;
  const int lane = tid & 63;
  const int wid  = __builtin_amdgcn_readfirstlane(tid >> 6);
  const int g    = wid & 3;           // token group
  const int h    = wid >> 2;          // K half
  const int lm   = lane & 15;         // A: token row / B: expert-in-16
  const int lk   = lane >> 4;         // k-group (8 bf16 each)
  const int tok0 = blockIdx.x * MTPB;

  unsigned short* shw = sh + wid * WPL;   // private region
  // staging map: lane -> (token row lane>>2, 16B f32 seg); 8 segs per round
  const float* ugw = u + (size_t)(tok0 + g * 16 + (lane >> 2)) * DM
                       + h * 1024 + (lane & 3) * 4;
  const int uoffw = (lane >> 2) * KS2 + (lane & 3) * 4;   // bf16 elems (+i*16)
  const int a_off = lm * KS2 + lk * 8;                    // A-frag (+p*32)

  f4v acc[4];
#pragma unroll
  for (int j = 0; j < 4; ++j) acc[j] = (f4v){0.f, 0.f, 0.f, 0.f};

  float4 pfA[8], pfB[8];
  LOADW(pfA, 0);
  WRITEW(pfA);                 // round 0 -> private LDS (same-wave, no barrier)
  LOADW(pfB, 1);

  s8v f0h[4], f0l[4], f1h[4], f1l[4];
  for (int r = 0; r < NR2; r += 2) {
    READF(f0h, f0l);                      // round r (in-order DS: reads precede
    if (r + 1 < NR2) WRITEW(pfB);         //  the overwrite by round r+1)
    if (r + 2 < NR2) LOADW(pfA, r + 2);
    COMP(r, f0h, f0l);

    READF(f1h, f1l);                      // round r+1 (just written, same wave)
    if (r + 2 < NR2) WRITEW(pfA);
    if (r + 3 < NR2) LOADW(pfB, r + 3);
    COMP(r + 1, f1h, f1l);
  }

  // ---- K-half reduction: fin[4 g][16 tok][68] (aliases sh; 17,408 B) ----
  // D frags: col=lane&15 <-> expert(j*16+lm), row=lk*4+q <-> token row.
  __syncthreads();                        // staging region reads all done
  float* fin = (float*)sh;
  if (h == 0) {
#pragma unroll
    for (int j = 0; j < 4; ++j)
#pragma unroll
      for (int q = 0; q < 4; ++q)
        fin[g * (16 * 68) + (lk * 4 + q) * 68 + j * 16 + lm] = acc[j][q];
  }
  __syncthreads();
  if (h == 1) {
#pragma unroll
    for (int j = 0; j < 4; ++j)
#pragma unroll
      for (int q = 0; q < 4; ++q)
        fin[g * (16 * 68) + (lk * 4 + q) * 68 + j * 16 + lm] += acc[j][q];
  }
  __syncthreads();

  // ---- epilogue: wave (g,h) -> tokens g*16 + h*8 ..+7, lane = expert ----
  const float be = bias[lane];
  float asum = 0.f;
  for (int tt = 0; tt < 8; ++tt) {
    const int tl = h * 8 + tt;            // row in group
    const int t  = g * 16 + tl;           // token in block
    float x = fin[g * (16 * 68) + tl * 68 + lane] + be;

    float m = x;
#pragma unroll
    for (int off = 32; off > 0; off >>= 1) m = fmaxf(m, __shfl_xor(m, off));
    float p = expf(x - m);
    float s = p;
#pragma unroll
    for (int off = 32; off > 0; off >>= 1) s += __shfl_xor(s, off);
    float sc = p / s;

    out[OFF_SC + (size_t)(tok0 + t) * NE + lane] = sc;
    asum += sc;

    float v = sc;
#pragma unroll
    for (int k = 0; k < TOPK; ++k) {
      float bv = v;
      int   bi = lane;
#pragma unroll
      for (int off = 32; off > 0; off >>= 1) {
        float ov = __shfl_xor(bv, off);
        int   oi = __shfl_xor(bi, off);
        if (ov > bv || (ov == bv && oi < bi)) { bv = ov; bi = oi; }
      }
      if (lane == k) {
        out[OFF_TI + (size_t)(tok0 + t) * TOPK + k] = (float)bi;
        out[OFF_TS + (size_t)(tok0 + t) * TOPK + k] = bv;
      }
      if (lane == bi) v = -INFINITY;
    }
  }
  atomicAdd(&ws[lane], asum);   // per-expert partial for aux loss

  // ---- folded aux: last block to finish reduces ws (device-scope ticket) ----
  __threadfence();
  __syncthreads();
  unsigned* flg = (unsigned*)sh;
  if (tid == 0) {
    const unsigned t = atomicAdd((unsigned*)&ws[NE], 1u);   // ws[64] = counter
    flg[17000] = (t == (unsigned)(gridDim.x - 1)) ? 1u : 0u;
  }
  __syncthreads();
  if (flg[17000] && tid < 64) {
    const float mv = atomicAdd(&ws[tid], 0.f) * (1.0f / N_TOK);  // coherent read
    float v = mv * mv;
#pragma unroll
    for (int off = 32; off > 0; off >>= 1) v += __shfl_xor(v, off);
    if (tid == 0) out[OFF_AUX] = v * (float)NE;
  }
}

// ---------------- fallback (ws too small): proven R1 kernel ----------------
#define TPB     64
#define FB_DC   32
#define FB_NCH  (1024 / FB_DC)
#define FB_LSTR 68
#define FB_UB   (TPB * FB_LSTR)
#define FB_EOFF (2 * FB_UB)
#define FB_EB   (2 * FB_DC * NE)

__global__ __launch_bounds__(1024, 4) void router_main_fb(
    const float* __restrict__ u, const float* __restrict__ E,
    const float* __restrict__ bias, float* __restrict__ out,
    float* __restrict__ ws)
{
  __shared__ float smem[FB_EOFF + 2 * FB_EB];

  const int tid  = threadIdx.x;
  const int lane = tid & 63;
  const int wid  = __builtin_amdgcn_readfirstlane(tid >> 6);
  const int eg   = wid & 7;
  const int kh   = wid >> 3;
  const int tok0 = blockIdx.x * TPB;

  const int stok  = tid >> 4;
  const int sdseg = tid & 15;
  const int skh   = sdseg >> 3;
  const int sdsub = (sdseg & 7) * 4;
  const float* sgbase = u + (size_t)(tok0 + stok) * DM + skh * 1024 + sdsub;
  float* swp = smem + stok * FB_LSTR + sdseg * 4;

  const int eq  = tid & 511;
  const int ekh = tid >> 9;
  const float* egbase = E + (size_t)ekh * 1024 * NE + eq * 4;
  float* ewp = smem + FB_EOFF + ekh * (FB_DC * NE) + eq * 4;

  float acc[8];
#pragma unroll
  for (int j = 0; j < 8; ++j) acc[j] = 0.f;

  float4 pf[3];
  pf[0] = *(const float4*)(sgbase + 0 * FB_DC);
  pf[1] = *(const float4*)(sgbase + 1 * FB_DC);
  pf[2] = *(const float4*)(sgbase + 2 * FB_DC);
  float4 epf = *(const float4*)(egbase + 0 * (FB_DC * NE));
  *(float4*)(swp + 0) = pf[0];
  *(float4*)(ewp + 0) = epf;
  epf = *(const float4*)(egbase + 1 * (FB_DC * NE));
  __syncthreads();

  for (int c = 0; c < FB_NCH; ++c) {
    if (c + 1 < FB_NCH) {
      *(float4*)(swp + ((c + 1) & 1) * FB_UB) = pf[(c + 1) % 3];
      *(float4*)(ewp + ((c + 1) & 1) * FB_EB) = epf;
    }
    if (c + 2 < FB_NCH)
      epf = *(const float4*)(egbase + (c + 2) * (FB_DC * NE));
    if (c + 3 < FB_NCH)
      pf[c % 3] = *(const float4*)(sgbase + (c + 3) * FB_DC);

    const float* sb = smem + (c & 1) * FB_UB + lane * FB_LSTR + kh * FB_DC;
    const float* eb = smem + FB_EOFF + (c & 1) * FB_EB + kh * (FB_DC * NE) + eg * 8;
#pragma unroll
    for (int s = 0; s < 8; ++s) {
      float4 uf = *(const float4*)(sb + s * 4);
#pragma unroll
      for (int dd = 0; dd < 4; ++dd) {
        const float* er = eb + (s * 4 + dd) * NE;
        float4 e0 = *(const float4*)(er);
        float4 e1 = *(const float4*)(er + 4);
        const float uv = (&uf.x)[dd];
        acc[0] = fmaf(e0.x, uv, acc[0]);
        acc[1] = fmaf(e0.y, uv, acc[1]);
        acc[2] = fmaf(e0.z, uv, acc[2]);
        acc[3] = fmaf(e0.w, uv, acc[3]);
        acc[4] = fmaf(e1.x, uv, acc[4]);
        acc[5] = fmaf(e1.y, uv, acc[5]);
        acc[6] = fmaf(e1.z, uv, acc[6]);
        acc[7] = fmaf(e1.w, uv, acc[7]);
      }
    }
    __syncthreads();
  }

  float* fin = smem;
  if (kh == 0) {
#pragma unroll
    for (int j = 0; j < 8; ++j) fin[lane * 65 + eg * 8 + j] = acc[j];
  }
  __syncthreads();
  if (kh == 1) {
#pragma unroll
    for (int j = 0; j < 8; ++j) fin[lane * 65 + eg * 8 + j] += acc[j];
  }
  __syncthreads();

  const float be = bias[lane];
  float asum = 0.f;
#pragma unroll
  for (int tt = 0; tt < 4; ++tt) {
    const int t = wid * 4 + tt;
    float x = fin[t * 65 + lane] + be;

    float m = x;
#pragma unroll
    for (int off = 32; off > 0; off >>= 1) m = fmaxf(m, __shfl_xor(m, off));
    float p = expf(x - m);
    float s = p;
#pragma unroll
    for (int off = 32; off > 0; off >>= 1) s += __shfl_xor(s, off);
    float sc = p / s;

    out[OFF_SC + (size_t)(tok0 + t) * NE + lane] = sc;
    asum += sc;

    float v = sc;
#pragma unroll
    for (int k = 0; k < TOPK; ++k) {
      float bv = v;
      int   bi = lane;
#pragma unroll
      for (int off = 32; off > 0; off >>= 1) {
        float ov = __shfl_xor(bv, off);
        int   oi = __shfl_xor(bi, off);
        if (ov > bv || (ov == bv && oi < bi)) { bv = ov; bi = oi; }
      }
      if (lane == k) {
        out[OFF_TI + (size_t)(tok0 + t) * TOPK + k] = (float)bi;
        out[OFF_TS + (size_t)(tok0 + t) * TOPK + k] = bv;
      }
      if (lane == bi) v = -INFINITY;
    }
  }
  atomicAdd(&ws[lane], asum);
}

__global__ void router_aux(const float* __restrict__ ws, float* __restrict__ out)
{
  const int lane = threadIdx.x & 63;
  float m = ws[lane] * (1.0f / N_TOK);
  float v = m * m;
#pragma unroll
  for (int off = 32; off > 0; off >>= 1) v += __shfl_xor(v, off);
  if (lane == 0) out[OFF_AUX] = v * (float)NE;
}

extern "C" void kernel_launch(void* const* d_in, const int* in_sizes, int n_in,
                              void* d_out, int out_size, void* d_ws, size_t ws_size,
                              hipStream_t stream) {
  const float* u    = (const float*)d_in[0];
  const float* E    = (const float*)d_in[1];
  const float* bias = (const float*)d_in[2];
  float* out = (float*)d_out;
  float* ws  = (float*)d_ws;

  if (ws_size >= WS_NEED) {
    unsigned short* eh = (unsigned short*)((char*)ws + EH_OFF);
    unsigned short* el = eh + ET_ELEMS;
    router_prep<<<DM / 32, 256, 0, stream>>>(E, eh, el, ws);
    router_main_mfma<<<N_TOK / MTPB, 512, 0, stream>>>(u, eh, el, bias, out, ws);
  } else {
    hipMemsetAsync(ws, 0, NE * sizeof(float), stream);
    router_main_fb<<<N_TOK / TPB, 1024, 0, stream>>>(u, E, bias, out, ws);
    router_aux<<<1, 64, 0, stream>>>(ws, out);
  }
}